// Round 8
// baseline (1092.375 us; speedup 1.0000x reference)
//
#include <hip/hip_runtime.h>
#include <math.h>

#define N_NODES 100000
#define R_REL   1000
#define T_TRI   600000
#define D_DIM   128
#define OUT_STRIDE 640
#define NBLK    512
#define NTHR    256

typedef unsigned int  u32;
typedef unsigned short u16;

__device__ __forceinline__ float wave_sum(float v) {
    #pragma unroll
    for (int off = 32; off > 0; off >>= 1) v += __shfl_xor(v, off);
    return v;
}
__device__ __forceinline__ float sub16_sum(float v) {
    v += __shfl_xor(v, 1); v += __shfl_xor(v, 2);
    v += __shfl_xor(v, 4); v += __shfl_xor(v, 8);
    return v;
}
__device__ __forceinline__ float fast_tanh(float x) {
    float e = __expf(2.f * x);
    return 1.f - __fdividef(2.f, e + 1.f);
}
__device__ __forceinline__ float4 tanh4(float4 v) {
    float4 o; o.x = fast_tanh(v.x); o.y = fast_tanh(v.y);
    o.z = fast_tanh(v.z); o.w = fast_tanh(v.w);
    return o;
}
__device__ __forceinline__ float dot4(float4 a, float4 b) {
    return a.x*b.x + a.y*b.y + a.z*b.z + a.w*b.w;
}
__device__ __forceinline__ u32 bfr(float x) {
    u32 u = __float_as_uint(x);
    return (u + 0x7fffu + ((u >> 16) & 1u)) >> 16;
}
__device__ __forceinline__ uint2 pack_bf4(float4 v) {
    uint2 p;
    p.x = bfr(v.x) | (bfr(v.y) << 16);
    p.y = bfr(v.z) | (bfr(v.w) << 16);
    return p;
}
__device__ __forceinline__ void unpack_bf8(uint4 v, float f[8]) {
    f[0] = __uint_as_float(v.x << 16); f[1] = __uint_as_float(v.x & 0xffff0000u);
    f[2] = __uint_as_float(v.y << 16); f[3] = __uint_as_float(v.y & 0xffff0000u);
    f[4] = __uint_as_float(v.z << 16); f[5] = __uint_as_float(v.z & 0xffff0000u);
    f[6] = __uint_as_float(v.w << 16); f[7] = __uint_as_float(v.w & 0xffff0000u);
}

// Device-scope grid barrier: counter is monotonically increasing within a
// launch (target = k*NBLK at the k-th barrier); host memsets it to 0 each call.
// __threadfence() is agent-scope on gfx950 (handles cross-XCD L2 wb/inv).
__device__ __forceinline__ void grid_barrier(u32* bar, u32 target) {
    __threadfence();
    __syncthreads();
    if (threadIdx.x == 0) {
        atomicAdd(bar, 1u);
        while (atomicAdd(bar, 0u) < target) __builtin_amdgcn_s_sleep(2);
    }
    __syncthreads();
    __threadfence();
}

// ---- per-row bodies (verbatim math from round-7 kernels) ----

__device__ __forceinline__ void nr_row(
    int wid, int lane, float* s_w, float* s_fs,
    float* __restrict__ outbuf, int out_off,
    const u16* __restrict__ in_bf, u16* __restrict__ out_bf,
    const int* __restrict__ row_ptr, const int* __restrict__ col,
    const int* __restrict__ ridx1, const float* __restrict__ r_val,
    const u16* __restrict__ rel_bf, const float* __restrict__ wtab,
    const float* __restrict__ fsc,
    const float* __restrict__ ha, float* __restrict__ eproj_out)
{
    int beg = row_ptr[wid], end = row_ptr[wid + 1];
    int deg = end - beg;
    float* orow = outbuf + (size_t)wid * OUT_STRIDE + out_off;
    int sg = lane >> 4, sl = lane & 15;

    if (deg == 0) {
        if (lane < 32) { float4 z = {0.f,0.f,0.f,0.f}; ((float4*)orow)[lane] = z; }
        if (out_bf != nullptr && lane < 16) {
            uint4 z = {0u,0u,0u,0u};
            ((uint4*)(out_bf + (size_t)wid * D_DIM))[lane] = z;
        }
        if (ha != nullptr && lane == 0) eproj_out[wid] = 1.f;   // exp(0)
        return;
    }

    int  t0 = beg + lane;
    bool va = t0 < end;
    int  ta = va ? t0 : beg;
    int  rt_a = ridx1[ta];
    float rv_a = r_val[ta];
    bool  z_a  = (rv_a == 0.f);
    float w_a  = z_a ? 1.f : wtab[rt_a];
    float fs_a = z_a ? 0.f : fsc[rt_a];
    w_a = va ? w_a : 0.f;

    int  tb0 = beg + sg, tb1 = tb0 + 4;
    bool v0 = tb0 < end, v1 = tb1 < end;
    int  tc0 = v0 ? tb0 : beg, tc1 = v1 ? tb1 : beg;
    int  cc0 = col[tc0],   cc1 = col[tc1];
    int  rr0 = ridx1[tc0], rr1 = ridx1[tc1];
    uint4 F0 = ((const uint4*)(in_bf  + (size_t)cc0 * D_DIM))[sl];
    uint4 R0 = ((const uint4*)(rel_bf + (size_t)rr0 * D_DIM))[sl];
    uint4 F1 = ((const uint4*)(in_bf  + (size_t)cc1 * D_DIM))[sl];
    uint4 R1 = ((const uint4*)(rel_bf + (size_t)rr1 * D_DIM))[sl];

    float lsum = w_a;
    for (int t = t0 + 64; t < end; t += 64) {
        int rt = ridx1[t]; float rv = r_val[t];
        lsum += (rv == 0.f) ? 1.f : wtab[rt];
    }
    float inv_s = 1.f / wave_sum(lsum);
    s_w[lane]  = w_a * inv_s;
    s_fs[lane] = fs_a;

    float w0  = v0 ? s_w[sg] : 0.f;
    float fs0 = s_fs[sg];
    float nf[8], rf[8];
    unpack_bf8(F0, nf); unpack_bf8(R0, rf);
    float pd = 0.f;
    #pragma unroll
    for (int j = 0; j < 8; ++j) pd += nf[j] * rf[j];
    pd = sub16_sum(pd);
    float f0 = fs0 * pd;
    float acc[8];
    #pragma unroll
    for (int j = 0; j < 8; ++j) acc[j] = w0 * (nf[j] - f0 * rf[j]);

    int niter = (deg + 3) >> 2;
    int cur_tc = tc1, cur_rr = rr1; bool cur_v = v1;
    for (int it = 1; it < niter; ++it) {
        int tb = beg + 4 * (it + 1) + sg;
        bool nv = tb < end;
        int  ntc = nv ? tb : beg;
        int  ncc = col[ntc];
        int  nrr = ridx1[ntc];
        uint4 NF = ((const uint4*)(in_bf  + (size_t)ncc * D_DIM))[sl];
        uint4 NR = ((const uint4*)(rel_bf + (size_t)nrr * D_DIM))[sl];

        int idx = 4 * it + sg;
        float w, fs;
        if (idx < 64) {
            w  = cur_v ? s_w[idx] : 0.f;
            fs = s_fs[idx];
        } else {
            float rv = r_val[cur_tc];
            bool z = (rv == 0.f);
            w  = cur_v ? (z ? 1.f : wtab[cur_rr]) * inv_s : 0.f;
            fs = z ? 0.f : fsc[cur_rr];
        }
        float gf[8], qf[8];
        unpack_bf8(F1, gf); unpack_bf8(R1, qf);
        float pdt = 0.f;
        #pragma unroll
        for (int j = 0; j < 8; ++j) pdt += gf[j] * qf[j];
        pdt = sub16_sum(pdt);
        float ft = fs * pdt;
        #pragma unroll
        for (int j = 0; j < 8; ++j) acc[j] += w * (gf[j] - ft * qf[j]);

        F1 = NF; R1 = NR;
        cur_tc = ntc; cur_rr = nrr; cur_v = nv;
    }

    #pragma unroll
    for (int j = 0; j < 8; ++j) {
        acc[j] += __shfl_xor(acc[j], 16);
        acc[j] += __shfl_xor(acc[j], 32);
    }
    float4 tv0 = tanh4(make_float4(acc[0], acc[1], acc[2], acc[3]));
    float4 tv1 = tanh4(make_float4(acc[4], acc[5], acc[6], acc[7]));
    if (sg == 0) ((float4*)orow)[2 * sl] = tv0;
    else if (sg == 1) ((float4*)orow)[2 * sl + 1] = tv1;
    if (out_bf != nullptr) {
        u16* rowbf = out_bf + (size_t)wid * D_DIM;
        if (sg == 0) ((uint2*)rowbf)[2 * sl] = pack_bf4(tv0);
        else if (sg == 1) ((uint2*)rowbf)[2 * sl + 1] = pack_bf4(tv1);
    }
    if (ha != nullptr) {
        const float4* ha4 = (const float4*)ha;
        float pdp = dot4(tv0, ha4[2 * sl]) + dot4(tv1, ha4[2 * sl + 1]);
        pdp = sub16_sum(pdp);
        if (lane == 0) eproj_out[wid] = __expf(pdp);
    }
}

__device__ __forceinline__ void high_row(
    int wid, int lane, float* s_w,
    float* __restrict__ outbuf, int out_off,
    const u16* __restrict__ in_bf, u16* __restrict__ out_bf,
    const int* __restrict__ row_ptr, const int* __restrict__ hcol,
    const float* __restrict__ eproj,
    const float* __restrict__ ha, float* __restrict__ eproj_out)
{
    int beg = row_ptr[wid], end = row_ptr[wid + 1];
    int deg = end - beg;
    float* orow = outbuf + (size_t)wid * OUT_STRIDE + out_off;
    int sg = lane >> 4, sl = lane & 15;

    if (deg == 0) {
        if (lane < 32) { float4 z = {0.f,0.f,0.f,0.f}; ((float4*)orow)[lane] = z; }
        if (out_bf != nullptr && lane < 16) {
            uint4 z = {0u,0u,0u,0u};
            ((uint4*)(out_bf + (size_t)wid * D_DIM))[lane] = z;
        }
        if (ha != nullptr && lane == 0) eproj_out[wid] = 1.f;
        return;
    }

    int  t0 = beg + lane;
    bool va = t0 < end;
    int  ta = va ? t0 : beg;
    int  c_a = hcol[ta];
    float e_a = eproj[c_a];
    e_a = va ? e_a : 0.f;

    int  tb0 = beg + sg, tb1 = tb0 + 4;
    bool v0 = tb0 < end, v1 = tb1 < end;
    int  tc0 = v0 ? tb0 : beg, tc1 = v1 ? tb1 : beg;
    int  cc0 = hcol[tc0], cc1 = hcol[tc1];
    uint4 F0 = ((const uint4*)(in_bf + (size_t)cc0 * D_DIM))[sl];
    uint4 F1 = ((const uint4*)(in_bf + (size_t)cc1 * D_DIM))[sl];

    float lsum = e_a;
    for (int t = t0 + 64; t < end; t += 64)
        lsum += eproj[hcol[t]];
    float inv_s = 1.f / wave_sum(lsum);
    s_w[lane] = e_a * inv_s;

    float w0 = v0 ? s_w[sg] : 0.f;
    float nf[8];
    unpack_bf8(F0, nf);
    float acc[8];
    #pragma unroll
    for (int j = 0; j < 8; ++j) acc[j] = w0 * nf[j];

    int niter = (deg + 3) >> 2;
    int cur_cc = cc1; bool cur_v = v1;
    for (int it = 1; it < niter; ++it) {
        int tb = beg + 4 * (it + 1) + sg;
        bool nv = tb < end;
        int  ntc = nv ? tb : beg;
        int  ncc = hcol[ntc];
        uint4 NF = ((const uint4*)(in_bf + (size_t)ncc * D_DIM))[sl];

        int idx = 4 * it + sg;
        float w;
        if (idx < 64) w = cur_v ? s_w[idx] : 0.f;
        else          w = cur_v ? eproj[cur_cc] * inv_s : 0.f;
        float gf[8];
        unpack_bf8(F1, gf);
        #pragma unroll
        for (int j = 0; j < 8; ++j) acc[j] += w * gf[j];

        F1 = NF; cur_cc = ncc; cur_v = nv;
    }

    #pragma unroll
    for (int j = 0; j < 8; ++j) {
        acc[j] += __shfl_xor(acc[j], 16);
        acc[j] += __shfl_xor(acc[j], 32);
    }
    float4 tv0 = tanh4(make_float4(acc[0], acc[1], acc[2], acc[3]));
    float4 tv1 = tanh4(make_float4(acc[4], acc[5], acc[6], acc[7]));
    if (sg == 0) ((float4*)orow)[2 * sl] = tv0;
    else if (sg == 1) ((float4*)orow)[2 * sl + 1] = tv1;
    if (out_bf != nullptr) {
        u16* rowbf = out_bf + (size_t)wid * D_DIM;
        if (sg == 0) ((uint2*)rowbf)[2 * sl] = pack_bf4(tv0);
        else if (sg == 1) ((uint2*)rowbf)[2 * sl + 1] = pack_bf4(tv1);
    }
    if (ha != nullptr) {
        const float4* ha4 = (const float4*)ha;
        float pdp = dot4(tv0, ha4[2 * sl]) + dot4(tv1, ha4[2 * sl + 1]);
        pdp = sub16_sum(pdp);
        if (lane == 0) eproj_out[wid] = __expf(pdp);
    }
}

// ---- fully fused pipeline: prep | bar | NR0 | bar | NR1 | bar | H0 | bar | H1 ----
__global__ __launch_bounds__(NTHR, 4) void k_fused(
    const float* __restrict__ features,
    const float* __restrict__ rel_emb,
    const float* __restrict__ r_val,
    const float* __restrict__ attk,
    const float* __restrict__ high_atts,
    const int* __restrict__ adj,
    const int* __restrict__ r_index,
    const int* __restrict__ high_nei,
    float* __restrict__ out,
    u32* __restrict__ bar,
    int* __restrict__ row_ptr_adj, int* __restrict__ row_ptr_high,
    float* __restrict__ wtab, float* __restrict__ fsc,
    float* __restrict__ eproj0, float* __restrict__ eproj1,
    u16* __restrict__ rel_bf,
    u16* __restrict__ fbf0, u16* __restrict__ fbf1,
    u16* __restrict__ fbf2, u16* __restrict__ fbf3)
{
    __shared__ float s_w[4][64];
    __shared__ float s_fs[4][64];
    int wslot = threadIdx.x >> 6;
    int lane  = threadIdx.x & 63;
    int gw    = blockIdx.x * 4 + wslot;            // global wave id, stride 2048
    int gt    = blockIdx.x * NTHR + threadIdx.x;   // global thread id, stride 131072
    const int* col   = adj + T_TRI;
    const int* ridx1 = r_index + T_TRI;
    const int* hcol  = high_nei + T_TRI;

    // ---- stage 0: prep (independent pieces) ----
    // relprep: wave per relation
    for (int r = gw; r < R_REL; r += NBLK * 4) {
        float a0 = rel_emb[r * D_DIM + lane], a1 = rel_emb[r * D_DIM + 64 + lane];
        float nrm2 = wave_sum(a0 * a0 + a1 * a1);
        float d0 = wave_sum(a0 * attk[lane] + a1 * attk[64 + lane]);
        float d1 = wave_sum(a0 * attk[D_DIM + lane] + a1 * attk[D_DIM + 64 + lane]);
        if (lane == 0) {
            float inv = __frsqrt_rn(nrm2);
            wtab[r]         = __expf(d0 * inv);
            wtab[R_REL + r] = __expf(d1 * inv);
            fsc[r] = 2.f * inv * inv;
        }
    }
    // pack_rel: thread per 8 dims
    for (int t = gt; t < R_REL * 16; t += NBLK * NTHR) {
        int r = t >> 4, k = t & 15;
        const float4* src = (const float4*)(rel_emb + (size_t)r * D_DIM + k * 8);
        uint2 pa = pack_bf4(src[0]), pb = pack_bf4(src[1]);
        uint4 o; o.x = pa.x; o.y = pa.y; o.z = pb.x; o.w = pb.y;
        ((uint4*)(rel_bf + (size_t)r * D_DIM))[k] = o;
    }
    // rowptr: thread per node (both edge arrays)
    for (int i = gt; i < 2 * (N_NODES + 1); i += NBLK * NTHR) {
        const int* rows; int* p; int n;
        if (i <= N_NODES) { rows = adj; p = row_ptr_adj; n = i; }
        else { rows = high_nei; p = row_ptr_high; n = i - (N_NODES + 1); }
        int lo = 0, hi = T_TRI;
        while (lo < hi) { int mid = (lo + hi) >> 1; if (rows[mid] < n) lo = mid + 1; else hi = mid; }
        p[n] = lo;
    }
    // tanh: thread per float4
    for (int i = gt; i < N_NODES * D_DIM / 4; i += NBLK * NTHR) {
        int n = i / (D_DIM / 4);
        int d4 = i % (D_DIM / 4);
        float4 v = reinterpret_cast<const float4*>(features)[i];
        float4 t = tanh4(v);
        reinterpret_cast<float4*>(out + (size_t)n * OUT_STRIDE)[d4] = t;
        reinterpret_cast<uint2*>(fbf0 + (size_t)n * D_DIM)[d4] = pack_bf4(t);
    }
    grid_barrier(bar, 1 * NBLK);

    // ---- stage 1: NR layer 0 ----
    for (int wid = gw; wid < N_NODES; wid += NBLK * 4)
        nr_row(wid, lane, s_w[wslot], s_fs[wslot], out, 1 * D_DIM, fbf0, fbf1,
               row_ptr_adj, col, ridx1, r_val, rel_bf, wtab + 0 * R_REL, fsc,
               nullptr, nullptr);
    grid_barrier(bar, 2 * NBLK);

    // ---- stage 2: NR layer 1 (+ eproj0 fusion) ----
    for (int wid = gw; wid < N_NODES; wid += NBLK * 4)
        nr_row(wid, lane, s_w[wslot], s_fs[wslot], out, 2 * D_DIM, fbf1, fbf2,
               row_ptr_adj, col, ridx1, r_val, rel_bf, wtab + 1 * R_REL, fsc,
               high_atts + 0 * D_DIM, eproj0);
    grid_barrier(bar, 3 * NBLK);

    // ---- stage 3: high layer 0 (+ eproj1 fusion) ----
    for (int wid = gw; wid < N_NODES; wid += NBLK * 4)
        high_row(wid, lane, s_w[wslot], out, 3 * D_DIM, fbf2, fbf3,
                 row_ptr_high, hcol, eproj0, high_atts + 1 * D_DIM, eproj1);
    grid_barrier(bar, 4 * NBLK);

    // ---- stage 4: high layer 1 ----
    for (int wid = gw; wid < N_NODES; wid += NBLK * 4)
        high_row(wid, lane, s_w[wslot], out, 4 * D_DIM, fbf3, nullptr,
                 row_ptr_high, hcol, eproj1, nullptr, nullptr);
}

extern "C" void kernel_launch(void* const* d_in, const int* in_sizes, int n_in,
                              void* d_out, int out_size, void* d_ws, size_t ws_size,
                              hipStream_t stream) {
    const float* features  = (const float*)d_in[0];
    const float* rel_emb   = (const float*)d_in[1];
    const float* r_val     = (const float*)d_in[2];
    const float* attk      = (const float*)d_in[3];
    const float* high_atts = (const float*)d_in[4];
    const int*   adj       = (const int*)d_in[5];
    const int*   r_index   = (const int*)d_in[6];
    const int*   high_nei  = (const int*)d_in[7];
    float* out = (float*)d_out;

    char* ws = (char*)d_ws;
    auto take = [&](size_t bytes) -> char* {
        char* p = ws;
        ws += (bytes + 255) & ~(size_t)255;
        return p;
    };
    u32*   bar          = (u32*)take(64);
    int*   row_ptr_adj  = (int*)take((N_NODES + 1) * sizeof(int));
    int*   row_ptr_high = (int*)take((N_NODES + 1) * sizeof(int));
    float* wtab         = (float*)take(2 * R_REL * sizeof(float));
    float* fsc          = (float*)take(R_REL * sizeof(float));
    float* eproj0       = (float*)take(N_NODES * sizeof(float));
    float* eproj1       = (float*)take(N_NODES * sizeof(float));
    u16*   rel_bf       = (u16*)take((size_t)R_REL * D_DIM * sizeof(u16));
    u16*   fbf0         = (u16*)take((size_t)N_NODES * D_DIM * sizeof(u16));
    u16*   fbf1         = (u16*)take((size_t)N_NODES * D_DIM * sizeof(u16));
    u16*   fbf2         = (u16*)take((size_t)N_NODES * D_DIM * sizeof(u16));
    u16*   fbf3         = (u16*)take((size_t)N_NODES * D_DIM * sizeof(u16));

    hipMemsetAsync(bar, 0, 64, stream);   // barrier counter (ws is poisoned 0xAA)
    k_fused<<<NBLK, NTHR, 0, stream>>>(
        features, rel_emb, r_val, attk, high_atts, adj, r_index, high_nei,
        out, bar, row_ptr_adj, row_ptr_high, wtab, fsc, eproj0, eproj1,
        rel_bf, fbf0, fbf1, fbf2, fbf3);
}

// Round 9
// 224.461 us; speedup vs baseline: 4.8667x; 4.8667x over previous
//
#include <hip/hip_runtime.h>
#include <math.h>

#define N_NODES 100000
#define R_REL   1000
#define T_TRI   600000
#define D_DIM   128
#define OUT_STRIDE 640

typedef unsigned int  u32;
typedef unsigned short u16;

__device__ __forceinline__ float wave_sum(float v) {
    #pragma unroll
    for (int off = 32; off > 0; off >>= 1) v += __shfl_xor(v, off);
    return v;
}
__device__ __forceinline__ float half32_sum(float v) {   // sum within 32-lane half
    v += __shfl_xor(v, 1); v += __shfl_xor(v, 2); v += __shfl_xor(v, 4);
    v += __shfl_xor(v, 8); v += __shfl_xor(v, 16);
    return v;
}
__device__ __forceinline__ float sub16_sum(float v) {
    v += __shfl_xor(v, 1); v += __shfl_xor(v, 2);
    v += __shfl_xor(v, 4); v += __shfl_xor(v, 8);
    return v;
}
__device__ __forceinline__ float fast_tanh(float x) {
    float e = __expf(2.f * x);
    return 1.f - __fdividef(2.f, e + 1.f);
}
__device__ __forceinline__ float4 tanh4(float4 v) {
    float4 o; o.x = fast_tanh(v.x); o.y = fast_tanh(v.y);
    o.z = fast_tanh(v.z); o.w = fast_tanh(v.w);
    return o;
}
__device__ __forceinline__ float dot4(float4 a, float4 b) {
    return a.x*b.x + a.y*b.y + a.z*b.z + a.w*b.w;
}
__device__ __forceinline__ u32 bfr(float x) {
    u32 u = __float_as_uint(x);
    return (u + 0x7fffu + ((u >> 16) & 1u)) >> 16;
}
__device__ __forceinline__ uint2 pack_bf4(float4 v) {
    uint2 p;
    p.x = bfr(v.x) | (bfr(v.y) << 16);
    p.y = bfr(v.z) | (bfr(v.w) << 16);
    return p;
}
__device__ __forceinline__ void unpack_bf8(uint4 v, float f[8]) {
    f[0] = __uint_as_float(v.x << 16); f[1] = __uint_as_float(v.x & 0xffff0000u);
    f[2] = __uint_as_float(v.y << 16); f[3] = __uint_as_float(v.y & 0xffff0000u);
    f[4] = __uint_as_float(v.z << 16); f[5] = __uint_as_float(v.z & 0xffff0000u);
    f[6] = __uint_as_float(v.w << 16); f[7] = __uint_as_float(v.w & 0xffff0000u);
}

__global__ void k_tanh(const float* __restrict__ feat, float* __restrict__ out,
                       u16* __restrict__ bf0) {
    int i = blockIdx.x * blockDim.x + threadIdx.x;
    if (i >= N_NODES * D_DIM / 4) return;
    int n  = i / (D_DIM / 4);
    int d4 = i % (D_DIM / 4);
    float4 v = reinterpret_cast<const float4*>(feat)[i];
    float4 t = tanh4(v);
    reinterpret_cast<float4*>(out + (size_t)n * OUT_STRIDE)[d4] = t;
    reinterpret_cast<uint2*>(bf0 + (size_t)n * D_DIM)[d4] = pack_bf4(t);
}

__global__ void k_relprep(const float* __restrict__ rel, const float* __restrict__ attk,
                          float* __restrict__ wtab, float* __restrict__ fsc) {
    int r = blockIdx.x;
    int lane = threadIdx.x;
    float a0 = rel[r * D_DIM + lane], a1 = rel[r * D_DIM + 64 + lane];
    float nrm2 = wave_sum(a0 * a0 + a1 * a1);
    float d0  = wave_sum(a0 * attk[lane] + a1 * attk[64 + lane]);
    float d1  = wave_sum(a0 * attk[D_DIM + lane] + a1 * attk[D_DIM + 64 + lane]);
    if (lane == 0) {
        float inv = __frsqrt_rn(nrm2);
        wtab[r]         = __expf(d0 * inv);
        wtab[R_REL + r] = __expf(d1 * inv);
        fsc[r] = 2.f * inv * inv;
    }
}

__global__ void k_pack_rel(const float* __restrict__ rel, u16* __restrict__ relbf) {
    int t = blockIdx.x * blockDim.x + threadIdx.x;
    if (t >= R_REL * 16) return;
    int r = t >> 4, k = t & 15;
    const float4* src = (const float4*)(rel + (size_t)r * D_DIM + k * 8);
    uint2 pa = pack_bf4(src[0]), pb = pack_bf4(src[1]);
    uint4 o; o.x = pa.x; o.y = pa.y; o.z = pb.x; o.w = pb.y;
    ((uint4*)(relbf + (size_t)r * D_DIM))[k] = o;
}

__global__ void k_rowptr2(const int* __restrict__ rows_a, const int* __restrict__ rows_b,
                          int* __restrict__ pa, int* __restrict__ pb) {
    int i = blockIdx.x * blockDim.x + threadIdx.x;
    const int* rows; int* p; int n;
    if (i <= N_NODES) { rows = rows_a; p = pa; n = i; }
    else {
        n = i - (N_NODES + 1);
        if (n > N_NODES) return;
        rows = rows_b; p = pb;
    }
    int lo = 0, hi = T_TRI;
    while (lo < hi) { int mid = (lo + hi) >> 1; if (rows[mid] < n) lo = mid + 1; else hi = mid; }
    p[n] = lo;
}

// TWO rows per wave: half = lane>>5 picks the row, 2 subgroups x 16 lanes per row,
// 8 dims/lane.  All butterflies stay within the 32-lane half (exec-safe under
// half-divergence).  Per-row epilogue work split across the row's 2 subgroups.
__global__ __launch_bounds__(256) void k_nr_layer(
    float* __restrict__ outbuf, int out_off,
    const u16* __restrict__ in_bf,
    u16* __restrict__ out_bf,
    const int* __restrict__ row_ptr,
    const int* __restrict__ col,
    const int* __restrict__ ridx1,
    const float* __restrict__ r_val,
    const u16* __restrict__ rel_bf,
    const float* __restrict__ wtab,
    const float* __restrict__ fsc,
    const float* __restrict__ ha,
    float* __restrict__ eproj_out) {
    __shared__ float s_w[4][64];
    __shared__ float s_fs[4][64];
    int wslot = threadIdx.x >> 6;
    int lane  = threadIdx.x & 63;
    int wid2  = (blockIdx.x * blockDim.x + threadIdx.x) >> 6;
    int row   = wid2 * 2 + (lane >> 5);
    if (row >= N_NODES) return;
    int ll  = lane & 31;              // lane within row
    int sgl = (lane >> 4) & 1;        // subgroup within row
    int sl  = lane & 15;
    int beg = row_ptr[row], end = row_ptr[row + 1];
    int deg = end - beg;
    float* orow = outbuf + (size_t)row * OUT_STRIDE + out_off;

    if (deg == 0) {
        float4 z = {0.f,0.f,0.f,0.f};
        ((float4*)orow)[ll] = z;
        if (out_bf != nullptr && ll < 16) {
            uint4 zz = {0u,0u,0u,0u};
            ((uint4*)(out_bf + (size_t)row * D_DIM))[ll] = zz;
        }
        if (ha != nullptr && ll == 0) eproj_out[row] = 1.f;
        return;
    }

    // ---- pass A: lane ll owns edge beg+ll (deg<=32 fast path) ----
    int  t0 = beg + ll;
    bool va = t0 < end;
    int  ta = va ? t0 : beg;
    int  rt_a = ridx1[ta];
    float rv_a = r_val[ta];
    bool  z_a  = (rv_a == 0.f);
    float w_a  = z_a ? 1.f : wtab[rt_a];
    float fs_a = z_a ? 0.f : fsc[rt_a];
    w_a = va ? w_a : 0.f;

    // ---- pre-issue iter0 + iter1 gathers (2 edges/iter per row) ----
    int  tb0 = beg + sgl, tb1 = beg + 2 + sgl;
    bool v0 = tb0 < end, v1 = tb1 < end;
    int  tc0 = v0 ? tb0 : beg, tc1 = v1 ? tb1 : beg;
    int  cc0 = col[tc0],   cc1 = col[tc1];
    int  rr0 = ridx1[tc0], rr1 = ridx1[tc1];
    uint4 F0 = ((const uint4*)(in_bf  + (size_t)cc0 * D_DIM))[sl];
    uint4 R0 = ((const uint4*)(rel_bf + (size_t)rr0 * D_DIM))[sl];
    uint4 F1 = ((const uint4*)(in_bf  + (size_t)cc1 * D_DIM))[sl];
    uint4 R1 = ((const uint4*)(rel_bf + (size_t)rr1 * D_DIM))[sl];

    // ---- row sum over the 32-lane half ----
    float lsum = w_a;
    for (int t = t0 + 32; t < end; t += 32) {      // deg>32 guard
        int rt = ridx1[t]; float rv = r_val[t];
        lsum += (rv == 0.f) ? 1.f : wtab[rt];
    }
    float inv_s = 1.f / half32_sum(lsum);
    s_w[wslot][lane]  = w_a * inv_s;               // edge ll of this row at slot lane
    s_fs[wslot][lane] = fs_a;

    int hb = lane & 32;                            // half base in LDS

    // ---- iter 0 compute ----
    float w0  = v0 ? s_w[wslot][hb + sgl] : 0.f;
    float fs0 = s_fs[wslot][hb + sgl];
    float nf[8], rf[8];
    unpack_bf8(F0, nf); unpack_bf8(R0, rf);
    float pd = 0.f;
    #pragma unroll
    for (int j = 0; j < 8; ++j) pd += nf[j] * rf[j];
    pd = sub16_sum(pd);
    float f0 = fs0 * pd;
    float acc[8];
    #pragma unroll
    for (int j = 0; j < 8; ++j) acc[j] = w0 * (nf[j] - f0 * rf[j]);

    // ---- steady state: 2-deep pipelined; halves may diverge (no cross-half ops) ----
    int niter = (deg + 1) >> 1;
    int cur_tc = tc1, cur_rr = rr1; bool cur_v = v1;
    for (int it = 1; it < niter; ++it) {
        int tb = beg + 2 * (it + 1) + sgl;
        bool nv = tb < end;
        int  ntc = nv ? tb : beg;
        int  ncc = col[ntc];
        int  nrr = ridx1[ntc];
        uint4 NF = ((const uint4*)(in_bf  + (size_t)ncc * D_DIM))[sl];
        uint4 NR = ((const uint4*)(rel_bf + (size_t)nrr * D_DIM))[sl];

        int idx = 2 * it + sgl;
        float w, fs;
        if (idx < 32) {
            w  = cur_v ? s_w[wslot][hb + idx] : 0.f;
            fs = s_fs[wslot][hb + idx];
        } else {                                   // deg>32 fallback
            float rv = r_val[cur_tc];
            bool z = (rv == 0.f);
            w  = cur_v ? (z ? 1.f : wtab[cur_rr]) * inv_s : 0.f;
            fs = z ? 0.f : fsc[cur_rr];
        }
        float gf[8], qf[8];
        unpack_bf8(F1, gf); unpack_bf8(R1, qf);
        float pdt = 0.f;
        #pragma unroll
        for (int j = 0; j < 8; ++j) pdt += gf[j] * qf[j];
        pdt = sub16_sum(pdt);
        float ft = fs * pdt;
        #pragma unroll
        for (int j = 0; j < 8; ++j) acc[j] += w * (gf[j] - ft * qf[j]);

        F1 = NF; R1 = NR;
        cur_tc = ntc; cur_rr = nrr; cur_v = nv;
    }

    // ---- combine the row's 2 subgroup partials ----
    #pragma unroll
    for (int j = 0; j < 8; ++j) acc[j] += __shfl_xor(acc[j], 16);

    // ---- epilogue: subgroup sgl owns float4 index 2*sl+sgl ----
    float4 q = (sgl == 0) ? make_float4(acc[0], acc[1], acc[2], acc[3])
                          : make_float4(acc[4], acc[5], acc[6], acc[7]);
    float4 tq = tanh4(q);
    ((float4*)orow)[2 * sl + sgl] = tq;
    if (out_bf != nullptr)
        ((uint2*)(out_bf + (size_t)row * D_DIM))[2 * sl + sgl] = pack_bf4(tq);
    if (ha != nullptr) {
        const float4* ha4 = (const float4*)ha;
        float pdp = dot4(tq, ha4[2 * sl + sgl]);
        pdp = sub16_sum(pdp);
        pdp += __shfl_xor(pdp, 16);
        if (ll == 0) eproj_out[row] = __expf(pdp);
    }
}

__global__ __launch_bounds__(256) void k_high_layer(
    float* __restrict__ outbuf, int out_off,
    const u16* __restrict__ in_bf,
    u16* __restrict__ out_bf,
    const int* __restrict__ row_ptr,
    const int* __restrict__ hcol,
    const float* __restrict__ eproj,
    const float* __restrict__ ha,
    float* __restrict__ eproj_out) {
    __shared__ float s_w[4][64];
    int wslot = threadIdx.x >> 6;
    int lane  = threadIdx.x & 63;
    int wid2  = (blockIdx.x * blockDim.x + threadIdx.x) >> 6;
    int row   = wid2 * 2 + (lane >> 5);
    if (row >= N_NODES) return;
    int ll  = lane & 31;
    int sgl = (lane >> 4) & 1;
    int sl  = lane & 15;
    int beg = row_ptr[row], end = row_ptr[row + 1];
    int deg = end - beg;
    float* orow = outbuf + (size_t)row * OUT_STRIDE + out_off;

    if (deg == 0) {
        float4 z = {0.f,0.f,0.f,0.f};
        ((float4*)orow)[ll] = z;
        if (out_bf != nullptr && ll < 16) {
            uint4 zz = {0u,0u,0u,0u};
            ((uint4*)(out_bf + (size_t)row * D_DIM))[ll] = zz;
        }
        if (ha != nullptr && ll == 0) eproj_out[row] = 1.f;
        return;
    }

    int  t0 = beg + ll;
    bool va = t0 < end;
    int  ta = va ? t0 : beg;
    int  c_a = hcol[ta];
    float e_a = eproj[c_a];
    e_a = va ? e_a : 0.f;

    int  tb0 = beg + sgl, tb1 = beg + 2 + sgl;
    bool v0 = tb0 < end, v1 = tb1 < end;
    int  tc0 = v0 ? tb0 : beg, tc1 = v1 ? tb1 : beg;
    int  cc0 = hcol[tc0], cc1 = hcol[tc1];
    uint4 F0 = ((const uint4*)(in_bf + (size_t)cc0 * D_DIM))[sl];
    uint4 F1 = ((const uint4*)(in_bf + (size_t)cc1 * D_DIM))[sl];

    float lsum = e_a;
    for (int t = t0 + 32; t < end; t += 32)        // deg>32 guard
        lsum += eproj[hcol[t]];
    float inv_s = 1.f / half32_sum(lsum);
    s_w[wslot][lane] = e_a * inv_s;

    int hb = lane & 32;

    float w0 = v0 ? s_w[wslot][hb + sgl] : 0.f;
    float nf[8];
    unpack_bf8(F0, nf);
    float acc[8];
    #pragma unroll
    for (int j = 0; j < 8; ++j) acc[j] = w0 * nf[j];

    int niter = (deg + 1) >> 1;
    int cur_cc = cc1; bool cur_v = v1;
    for (int it = 1; it < niter; ++it) {
        int tb = beg + 2 * (it + 1) + sgl;
        bool nv = tb < end;
        int  ntc = nv ? tb : beg;
        int  ncc = hcol[ntc];
        uint4 NF = ((const uint4*)(in_bf + (size_t)ncc * D_DIM))[sl];

        int idx = 2 * it + sgl;
        float w;
        if (idx < 32) w = cur_v ? s_w[wslot][hb + idx] : 0.f;
        else          w = cur_v ? eproj[cur_cc] * inv_s : 0.f;
        float gf[8];
        unpack_bf8(F1, gf);
        #pragma unroll
        for (int j = 0; j < 8; ++j) acc[j] += w * gf[j];

        F1 = NF; cur_cc = ncc; cur_v = nv;
    }

    #pragma unroll
    for (int j = 0; j < 8; ++j) acc[j] += __shfl_xor(acc[j], 16);

    float4 q = (sgl == 0) ? make_float4(acc[0], acc[1], acc[2], acc[3])
                          : make_float4(acc[4], acc[5], acc[6], acc[7]);
    float4 tq = tanh4(q);
    ((float4*)orow)[2 * sl + sgl] = tq;
    if (out_bf != nullptr)
        ((uint2*)(out_bf + (size_t)row * D_DIM))[2 * sl + sgl] = pack_bf4(tq);
    if (ha != nullptr) {
        const float4* ha4 = (const float4*)ha;
        float pdp = dot4(tq, ha4[2 * sl + sgl]);
        pdp = sub16_sum(pdp);
        pdp += __shfl_xor(pdp, 16);
        if (ll == 0) eproj_out[row] = __expf(pdp);
    }
}

extern "C" void kernel_launch(void* const* d_in, const int* in_sizes, int n_in,
                              void* d_out, int out_size, void* d_ws, size_t ws_size,
                              hipStream_t stream) {
    const float* features  = (const float*)d_in[0];
    const float* rel_emb   = (const float*)d_in[1];
    const float* r_val     = (const float*)d_in[2];
    const float* attk      = (const float*)d_in[3];
    const float* high_atts = (const float*)d_in[4];
    const int*   adj       = (const int*)d_in[5];
    const int*   r_index   = (const int*)d_in[6];
    const int*   high_nei  = (const int*)d_in[7];
    float* out = (float*)d_out;

    char* ws = (char*)d_ws;
    auto take = [&](size_t bytes) -> char* {
        char* p = ws;
        ws += (bytes + 255) & ~(size_t)255;
        return p;
    };
    int*   row_ptr_adj  = (int*)take((N_NODES + 1) * sizeof(int));
    int*   row_ptr_high = (int*)take((N_NODES + 1) * sizeof(int));
    float* wtab         = (float*)take(2 * R_REL * sizeof(float));
    float* fsc          = (float*)take(R_REL * sizeof(float));
    float* eproj0       = (float*)take(N_NODES * sizeof(float));
    float* eproj1       = (float*)take(N_NODES * sizeof(float));
    u16*   rel_bf       = (u16*)take((size_t)R_REL * D_DIM * sizeof(u16));
    u16*   fbf0         = (u16*)take((size_t)N_NODES * D_DIM * sizeof(u16));
    u16*   fbf1         = (u16*)take((size_t)N_NODES * D_DIM * sizeof(u16));
    u16*   fbf2         = (u16*)take((size_t)N_NODES * D_DIM * sizeof(u16));
    u16*   fbf3         = (u16*)take((size_t)N_NODES * D_DIM * sizeof(u16));

    k_tanh<<<(N_NODES * D_DIM / 4 + 255) / 256, 256, 0, stream>>>(features, out, fbf0);
    k_relprep<<<R_REL, 64, 0, stream>>>(rel_emb, attk, wtab, fsc);
    k_pack_rel<<<(R_REL * 16 + 255) / 256, 256, 0, stream>>>(rel_emb, rel_bf);
    k_rowptr2<<<(2 * (N_NODES + 1) + 255) / 256, 256, 0, stream>>>(
        adj, high_nei, row_ptr_adj, row_ptr_high);

    int pair_blocks = ((N_NODES + 1) / 2 + 3) / 4;   // 2 rows/wave, 4 waves/block

    k_nr_layer<<<pair_blocks, 256, 0, stream>>>(
        out, 1 * D_DIM, fbf0, fbf1,
        row_ptr_adj, adj + T_TRI, r_index + T_TRI, r_val,
        rel_bf, wtab + 0 * R_REL, fsc, nullptr, nullptr);
    k_nr_layer<<<pair_blocks, 256, 0, stream>>>(
        out, 2 * D_DIM, fbf1, fbf2,
        row_ptr_adj, adj + T_TRI, r_index + T_TRI, r_val,
        rel_bf, wtab + 1 * R_REL, fsc, high_atts + 0 * D_DIM, eproj0);
    k_high_layer<<<pair_blocks, 256, 0, stream>>>(
        out, 3 * D_DIM, fbf2, fbf3,
        row_ptr_high, high_nei + T_TRI, eproj0, high_atts + 1 * D_DIM, eproj1);
    k_high_layer<<<pair_blocks, 256, 0, stream>>>(
        out, 4 * D_DIM, fbf3, nullptr,
        row_ptr_high, high_nei + T_TRI, eproj1, nullptr, nullptr);
}